// Round 3
// baseline (211.192 us; speedup 1.0000x reference)
//
#include <hip/hip_runtime.h>

#define SEQ_T 2048
#define NHEAD 16

typedef unsigned short u16;
typedef __attribute__((ext_vector_type(4))) float f32x4;
typedef __attribute__((ext_vector_type(8))) short short8;
typedef __attribute__((ext_vector_type(4))) unsigned short u16x4;

__device__ __forceinline__ u16 f2bf(float f) {
  unsigned u = __float_as_uint(f);
  unsigned r = (u + 0x7FFFu + ((u >> 16) & 1u)) >> 16;
  return (u16)r;
}

__device__ __forceinline__ void gload_lds16(const void* g, void* l) {
  __builtin_amdgcn_global_load_lds((const __attribute__((address_space(1))) void*)g,
                                   (__attribute__((address_space(3))) void*)l, 16, 0, 0);
}

// ---------------------------------------------------------------- convert
__global__ __launch_bounds__(256) void cvt_all(
    const float* __restrict__ x, const float* __restrict__ wq, const float* __restrict__ wk,
    const float* __restrict__ wv, const float* __restrict__ wo,
    u16* __restrict__ xb, u16* __restrict__ wqb, u16* __restrict__ wkb,
    u16* __restrict__ wvb, u16* __restrict__ wob) {
  const int bid = blockIdx.x;
  const float* s; u16* d; int base;
  if (bid < 4096) { s = x; d = xb; base = bid; }
  else {
    const int w = (bid - 4096) >> 10;
    base = (bid - 4096) & 1023;
    if (w == 0)      { s = wq; d = wqb; }
    else if (w == 1) { s = wk; d = wkb; }
    else if (w == 2) { s = wv; d = wvb; }
    else             { s = wo; d = wob; }
  }
  const int i = base * 256 + threadIdx.x;
  const float4 v = ((const float4*)s)[i];
  u16x4 o;
  o[0] = f2bf(v.x); o[1] = f2bf(v.y); o[2] = f2bf(v.z); o[3] = f2bf(v.w);
  ((u16x4*)d)[i] = o;
}

// ------------------------------------------------- shared GEMM main loop (128x128)
static __device__ __forceinline__ void gemm_core(
    const u16* __restrict__ A, const u16* __restrict__ Bmat,
    u16* lds, int row0, int col0, int tid, f32x4 acc[4][4]) {
  const int wv = tid >> 6, lane = tid & 63;
  const int wr = wv >> 1, wc = wv & 1;
  const int lr15 = lane & 15, lg = lane >> 4;

  auto stage = [&](int buf, int kt) {
    const int k0 = kt * 32;
#pragma unroll
    for (int v = 0; v < 2; ++v) {
      const int slot = v * 256 + tid;
      const int r = slot >> 2, c = slot & 3;
      const int sc = c ^ (r & 3);
      const u16* gA = A    + (size_t)(row0 + r) * 1024 + k0 + sc * 8;
      const u16* gB = Bmat + (size_t)(col0 + r) * 1024 + k0 + sc * 8;
      gload_lds16(gA, lds + buf * 8192 +        v * 2048 + wv * 512);
      gload_lds16(gB, lds + buf * 8192 + 4096 + v * 2048 + wv * 512);
    }
  };

  stage(0, 0);
  __syncthreads();
  for (int t = 0; t < 32; ++t) {
    if (t < 31) stage((t + 1) & 1, t + 1);
    const u16* lA = lds + (t & 1) * 8192;
    const u16* lB = lA + 4096;
    short8 a[4], b[4];
#pragma unroll
    for (int m = 0; m < 4; ++m) {
      const int row = wr * 64 + m * 16 + lr15;
      const int swz = lg ^ (row & 3);
      a[m] = *(const short8*)(lA + row * 32 + swz * 8);
    }
#pragma unroll
    for (int n = 0; n < 4; ++n) {
      const int row = wc * 64 + n * 16 + lr15;
      const int swz = lg ^ (row & 3);
      b[n] = *(const short8*)(lB + row * 32 + swz * 8);
    }
    __builtin_amdgcn_s_setprio(1);
#pragma unroll
    for (int m = 0; m < 4; ++m)
#pragma unroll
      for (int n = 0; n < 4; ++n)
        acc[m][n] = __builtin_amdgcn_mfma_f32_16x16x32_bf16(a[m], b[n], acc[m][n], 0, 0, 0);
    __builtin_amdgcn_s_setprio(0);
    __syncthreads();
  }
}

// ---------------------------------------------------- fused QKV projection
// Q is additionally scaled by -0.125*log2(e) so attn sigmoid = rcp(1+exp2(s)).
__global__ __launch_bounds__(256) void gemm_qkv(
    const u16* __restrict__ X,
    const u16* __restrict__ WQ, const u16* __restrict__ WK, const u16* __restrict__ WV,
    const float* __restrict__ BQ, const float* __restrict__ BK, const float* __restrict__ BV,
    u16* __restrict__ OQ, u16* __restrict__ OK, u16* __restrict__ OV) {
  __shared__ u16 lds[2 * 2 * 4096];
  const int which = blockIdx.x >> 3;
  const int col0 = (blockIdx.x & 7) * 128;
  const int row0 = blockIdx.y * 128;
  const u16* W = (which == 0) ? WQ : ((which == 1) ? WK : WV);
  const float* bias = (which == 0) ? BQ : ((which == 1) ? BK : BV);
  u16* out = (which == 0) ? OQ : ((which == 1) ? OK : OV);
  const int tid = threadIdx.x;
  f32x4 acc[4][4];
#pragma unroll
  for (int m = 0; m < 4; ++m)
#pragma unroll
    for (int n = 0; n < 4; ++n) acc[m][n] = (f32x4){0.f, 0.f, 0.f, 0.f};

  gemm_core(X, W, lds, row0, col0, tid, acc);

  const float qscale = (which == 0) ? -0.18033688011112042f : 1.0f;
  const int wv = tid >> 6, lane = tid & 63;
  const int wr = wv >> 1, wc = wv & 1;
#pragma unroll
  for (int n = 0; n < 4; ++n) {
    const int col = col0 + wc * 64 + n * 16 + (lane & 15);
    const float bc = bias[col];
    const int hh = col >> 6, hd = col & 63;
#pragma unroll
    for (int m = 0; m < 4; ++m) {
#pragma unroll
      for (int r = 0; r < 4; ++r) {
        const int row = row0 + wr * 64 + m * 16 + (lane >> 4) * 4 + r;
        const int b_ = row >> 11, tt = row & 2047;
        const u16 h = f2bf((acc[m][n][r] + bc) * qscale);
        if (which != 2) {
          out[(((size_t)(b_ * NHEAD + hh) * SEQ_T + tt) << 6) + hd] = h;
        } else {
          out[(((size_t)(b_ * NHEAD + hh) << 6) + hd) * SEQ_T + tt] = h;
        }
      }
    }
  }
}

// ------------------------------------------------------ sigmoid attention
// grid (32, 32): x = q-tile of 64 rows, y = b*H+h. 4 waves x 16 q-rows.
// Swapped QK^T with sigma-permuted K rows in LDS so the sigmoid results pack
// IN-REGISTER (cvt_pk) directly into the PV A-fragment: no P-LDS round trip.
// sigma(u): bit-shuffle a4<-u3, a3<-u2, a2<-u4 (self-inverse-free bijection);
// V staged identity, so P element at A-slot a multiplies V row a. den = P.1.
__device__ __forceinline__ int sigp(int u) {
  return (u & 35) | ((u & 8) << 1) | ((u & 4) << 1) | ((u & 16) >> 2);
}

__global__ __launch_bounds__(256) void attn_sig(
    const u16* __restrict__ Q, const u16* __restrict__ K,
    const u16* __restrict__ Vt, u16* __restrict__ AO) {
  __shared__ u16 ldsK[2][4096];   // [64 s(perm)][64 hd], chunk^(row&7) swizzle
  __shared__ u16 ldsV[2][4096];   // [64 hd][64 s], same swizzle
  const int tid = threadIdx.x, wv = tid >> 6, lane = tid & 63;
  const int lr15 = lane & 15, lg = lane >> 4;
  const int bh = blockIdx.y;
  const int q0 = blockIdx.x * 64 + wv * 16;
  const u16* Qb = Q  + (size_t)bh * SEQ_T * 64;
  const u16* Kb = K  + (size_t)bh * SEQ_T * 64;
  const u16* Vb = Vt + (size_t)bh * 64 * SEQ_T;

  short8 qf[2];
#pragma unroll
  for (int kk = 0; kk < 2; ++kk)
    qf[kk] = *(const short8*)(Qb + (size_t)(q0 + lr15) * 64 + kk * 32 + lg * 8);

  short8 onesf;
#pragma unroll
  for (int i = 0; i < 8; ++i) onesf[i] = (short)0x3F80;

  f32x4 oacc[4];
#pragma unroll
  for (int n = 0; n < 4; ++n) oacc[n] = (f32x4){0.f, 0.f, 0.f, 0.f};
  f32x4 dacc = (f32x4){0.f, 0.f, 0.f, 0.f};

  // staging constants: slot = v*256+tid; r = slot>>3; c = slot&7; r(v=1)=r+32
  const int r0 = tid >> 3, c0 = tid & 7;
  const int sc0 = c0 ^ (r0 & 7);
  const int sg0 = sigp(r0);            // sigma(r0+32) = sigma(r0)+32

  auto stage = [&](int buf, int s0) {
    gload_lds16(Kb + (size_t)(s0 + sg0) * 64 + sc0 * 8,        &ldsK[buf][wv * 512]);
    gload_lds16(Vb + (size_t)r0 * SEQ_T + s0 + sc0 * 8,        &ldsV[buf][wv * 512]);
    gload_lds16(Kb + (size_t)(s0 + sg0 + 32) * 64 + sc0 * 8,   &ldsK[buf][2048 + wv * 512]);
    gload_lds16(Vb + (size_t)(r0 + 32) * SEQ_T + s0 + sc0 * 8, &ldsV[buf][2048 + wv * 512]);
  };

  stage(0, 0);
  __syncthreads();

  for (int st = 0; st < 32; ++st) {
    if (st < 31) stage((st + 1) & 1, (st + 1) * 64);
    const u16* lK = ldsK[st & 1];
    const u16* lV = ldsV[st & 1];

    // S^T[64s' x 16t] = K(perm) . Q^T   (lane: t=lr15, s' = n*16 + lg*4 + r)
    f32x4 sacc[4];
#pragma unroll
    for (int n = 0; n < 4; ++n) sacc[n] = (f32x4){0.f, 0.f, 0.f, 0.f};
    __builtin_amdgcn_s_setprio(1);
#pragma unroll
    for (int kk = 0; kk < 2; ++kk) {
#pragma unroll
      for (int n = 0; n < 4; ++n) {
        const int row = n * 16 + lr15;
        const int swz = (kk * 4 + lg) ^ (row & 7);
        const short8 kf = *(const short8*)(lK + row * 64 + swz * 8);
        sacc[n] = __builtin_amdgcn_mfma_f32_16x16x32_bf16(kf, qf[kk], sacc[n], 0, 0, 0);
      }
    }
    __builtin_amdgcn_s_setprio(0);

    // sigmoid (Q pre-scaled: g = 1/(1+2^s)) -> pack straight into PV A-frags
    unsigned w[8];
#pragma unroll
    for (int n = 0; n < 4; ++n) {
      const float g0 = __builtin_amdgcn_rcpf(1.0f + __builtin_amdgcn_exp2f(sacc[n][0]));
      const float g1 = __builtin_amdgcn_rcpf(1.0f + __builtin_amdgcn_exp2f(sacc[n][1]));
      const float g2 = __builtin_amdgcn_rcpf(1.0f + __builtin_amdgcn_exp2f(sacc[n][2]));
      const float g3 = __builtin_amdgcn_rcpf(1.0f + __builtin_amdgcn_exp2f(sacc[n][3]));
      asm("v_cvt_pk_bf16_f32 %0, %1, %2" : "=v"(w[n * 2 + 0]) : "v"(g0), "v"(g1));
      asm("v_cvt_pk_bf16_f32 %0, %1, %2" : "=v"(w[n * 2 + 1]) : "v"(g2), "v"(g3));
    }
    union { unsigned u[4]; short8 s; } cv0, cv1;
    cv0.u[0] = w[0]; cv0.u[1] = w[1]; cv0.u[2] = w[2]; cv0.u[3] = w[3];
    cv1.u[0] = w[4]; cv1.u[1] = w[5]; cv1.u[2] = w[6]; cv1.u[3] = w[7];

    // O += P.V ; den += P.1
    __builtin_amdgcn_s_setprio(1);
#pragma unroll
    for (int kk = 0; kk < 2; ++kk) {
      const short8 pf = kk ? cv1.s : cv0.s;
#pragma unroll
      for (int m = 0; m < 4; ++m) {
        const int vr = m * 16 + lr15;
        const int vswz = (kk * 4 + lg) ^ (vr & 7);
        const short8 vf = *(const short8*)(lV + vr * 64 + vswz * 8);
        oacc[m] = __builtin_amdgcn_mfma_f32_16x16x32_bf16(pf, vf, oacc[m], 0, 0, 0);
      }
      dacc = __builtin_amdgcn_mfma_f32_16x16x32_bf16(pf, onesf, dacc, 0, 0, 0);
    }
    __builtin_amdgcn_s_setprio(0);
    __syncthreads();
  }

  const int b_ = bh >> 4, hh = bh & 15;
  f32x4 rden;
#pragma unroll
  for (int r = 0; r < 4; ++r) rden[r] = __builtin_amdgcn_rcpf(dacc[r] + 1e-6f);
#pragma unroll
  for (int n = 0; n < 4; ++n) {
    const int hd = n * 16 + lr15;
#pragma unroll
    for (int r = 0; r < 4; ++r) {
      const int tt = q0 + lg * 4 + r;
      const float o = oacc[n][r] * rden[r];
      AO[((size_t)(b_ * SEQ_T + tt) << 10) + hh * 64 + hd] = f2bf(o);
    }
  }
}

// ------------------------------------------- output projection + residual
__global__ __launch_bounds__(256) void gemm_out(
    const u16* __restrict__ A, const u16* __restrict__ W,
    const float* __restrict__ bias, const float* __restrict__ X,
    const float* __restrict__ alphap, float* __restrict__ out) {
  __shared__ u16 lds[2 * 6144];   // per buf: A 64x32 (2048) + B 128x32 (4096)
  const int col0 = blockIdx.x * 128, row0 = blockIdx.y * 64;
  const int tid = threadIdx.x, wv = tid >> 6, lane = tid & 63;
  const int lr15 = lane & 15, lg = lane >> 4;
  f32x4 acc[4][2];
#pragma unroll
  for (int m = 0; m < 4; ++m)
#pragma unroll
    for (int n = 0; n < 2; ++n) acc[m][n] = (f32x4){0.f, 0.f, 0.f, 0.f};

  auto stage = [&](int buf, int kt) {
    const int k0 = kt * 32;
    {
      const int r = tid >> 2, c = tid & 3;
      const int sc = c ^ (r & 3);
      gload_lds16(A + (size_t)(row0 + r) * 1024 + k0 + sc * 8, lds + buf * 6144 + wv * 512);
    }
#pragma unroll
    for (int v = 0; v < 2; ++v) {
      const int slot = v * 256 + tid;
      const int r = slot >> 2, c = slot & 3;
      const int sc = c ^ (r & 3);
      gload_lds16(W + (size_t)(col0 + r) * 1024 + k0 + sc * 8,
                  lds + buf * 6144 + 2048 + v * 2048 + wv * 512);
    }
  };

  stage(0, 0);
  __syncthreads();
  for (int t = 0; t < 32; ++t) {
    if (t < 31) stage((t + 1) & 1, t + 1);
    const u16* lA = lds + (t & 1) * 6144;
    const u16* lB = lA + 2048;
    short8 a[4], b[2];
#pragma unroll
    for (int m = 0; m < 4; ++m) {
      const int row = m * 16 + lr15;
      a[m] = *(const short8*)(lA + row * 32 + (lg ^ (row & 3)) * 8);
    }
#pragma unroll
    for (int n = 0; n < 2; ++n) {
      const int row = wv * 32 + n * 16 + lr15;
      b[n] = *(const short8*)(lB + row * 32 + (lg ^ (row & 3)) * 8);
    }
    __builtin_amdgcn_s_setprio(1);
#pragma unroll
    for (int m = 0; m < 4; ++m)
#pragma unroll
      for (int n = 0; n < 2; ++n)
        acc[m][n] = __builtin_amdgcn_mfma_f32_16x16x32_bf16(a[m], b[n], acc[m][n], 0, 0, 0);
    __builtin_amdgcn_s_setprio(0);
    __syncthreads();
  }

  const float alpha = alphap[0];
#pragma unroll
  for (int n = 0; n < 2; ++n) {
    const int col = col0 + wv * 32 + n * 16 + lr15;
    const float bc = bias[col];
#pragma unroll
    for (int m = 0; m < 4; ++m) {
#pragma unroll
      for (int r = 0; r < 4; ++r) {
        const int row = row0 + m * 16 + lg * 4 + r;
        const size_t off = ((size_t)row << 10) + col;
        out[off] = X[off] + alpha * (acc[m][n][r] + bc);
      }
    }
  }
}

// ------------------------------------------------------------------ launch
extern "C" void kernel_launch(void* const* d_in, const int* in_sizes, int n_in,
                              void* d_out, int out_size, void* d_ws, size_t ws_size,
                              hipStream_t stream) {
  const float* x  = (const float*)d_in[0];
  const float* wq = (const float*)d_in[1];
  const float* bq = (const float*)d_in[2];
  const float* wk = (const float*)d_in[3];
  const float* bk = (const float*)d_in[4];
  const float* wv = (const float*)d_in[5];
  const float* bv = (const float*)d_in[6];
  const float* wo = (const float*)d_in[7];
  const float* bo = (const float*)d_in[8];
  const float* alpha = (const float*)d_in[9];
  float* out = (float*)d_out;
  char* ws = (char*)d_ws;
  const size_t MB = 1u << 20;
  u16* xb  = (u16*)(ws + 0 * MB);
  u16* wqb = (u16*)(ws + 8 * MB);
  u16* wkb = (u16*)(ws + 10 * MB);
  u16* wvb = (u16*)(ws + 12 * MB);
  u16* wob = (u16*)(ws + 14 * MB);
  u16* qw  = (u16*)(ws + 16 * MB);   // [B,H,T,64] (scaled by -log2e/8)
  u16* kw  = (u16*)(ws + 24 * MB);   // [B,H,T,64]
  u16* vtw = (u16*)(ws + 32 * MB);   // [B,H,64,T]
  u16* aow = (u16*)(ws + 40 * MB);   // [4096,1024]

  cvt_all<<<8192, 256, 0, stream>>>(x, wq, wk, wv, wo, xb, wqb, wkb, wvb, wob);
  gemm_qkv<<<dim3(24, 32), 256, 0, stream>>>(xb, wqb, wkb, wvb, bq, bk, bv, qw, kw, vtw);
  attn_sig<<<dim3(32, 32), 256, 0, stream>>>(qw, kw, vtw, aow);
  gemm_out<<<dim3(8, 64), 256, 0, stream>>>(aow, wob, bo, x, alpha, out);
}